// Round 3
// baseline (1607.468 us; speedup 1.0000x reference)
//
#include <hip/hip_runtime.h>
#include <stdint.h>

// Problem constants: x [B=32, C=512, H=32, W=32] fp32, 32 groups, S = H*W = 1024.
// ALL inputs/outputs are FLOAT32 (per reference jnp.float32; round-2 analysis:
// threshold 0.10875 == 0.02*max|ref| exactly => no bf16 floor => fp32 I/O).
// Internal q/k/v/P/o are stored bf16 (our choice) for bandwidth + future MFMA.
#define Bsz 32
#define Cch 512
#define Ssp 1024
#define Grp 32
#define CPG 16

typedef unsigned short u16;

__device__ __forceinline__ float bf2f(u16 u) {
  union { float f; uint32_t i; } w; w.i = ((uint32_t)u) << 16; return w.f;
}
__device__ __forceinline__ u16 f2bf(float f) {
  union { float f; uint32_t i; } w; w.f = f;
  uint32_t r = w.i + 0x7fffu + ((w.i >> 16) & 1u);  // RNE
  return (u16)(r >> 16);
}

// 8-element loads -> fp32, overloaded on source dtype.
__device__ __forceinline__ void load8(const float* p, float* d) {
  float4 a = *(const float4*)p;
  float4 b = *(const float4*)(p + 4);
  d[0] = a.x; d[1] = a.y; d[2] = a.z; d[3] = a.w;
  d[4] = b.x; d[5] = b.y; d[6] = b.z; d[7] = b.w;
}
__device__ __forceinline__ void load8(const u16* p, float* d) {
  uint4 u = *(const uint4*)p;
  const u16* q = (const u16*)&u;
#pragma unroll
  for (int e = 0; e < 8; ++e) d[e] = bf2f(q[e]);
}

// ---------------- GN stats: one block per (b,g); emits per-channel affine ----
// stats[b*512 + c] = (A, B) with A = scale[c]*rstd, B = bias[c] - mean*A,
// so GN(x)[c][s] = x[c][s]*A + B.
__global__ __launch_bounds__(256) void gnstats_kernel(
    const float* __restrict__ x, const float* __restrict__ scale,
    const float* __restrict__ bias, float2* __restrict__ stats) {
  int b = blockIdx.x >> 5;
  int g = blockIdx.x & 31;
  size_t base = ((size_t)b * Cch + (size_t)g * CPG) * Ssp;
  const float4* xv = (const float4*)(x + base);  // 16384 floats = 4096 float4

  float sum = 0.f, sumsq = 0.f;
#pragma unroll
  for (int it = 0; it < 16; ++it) {
    float4 v = xv[threadIdx.x + 256 * it];
    sum += (v.x + v.y) + (v.z + v.w);
    sumsq += (v.x * v.x + v.y * v.y) + (v.z * v.z + v.w * v.w);
  }
#pragma unroll
  for (int off = 32; off > 0; off >>= 1) {
    sum += __shfl_xor(sum, off);
    sumsq += __shfl_xor(sumsq, off);
  }
  __shared__ float sm[8];
  int wid = threadIdx.x >> 6;
  if ((threadIdx.x & 63) == 0) { sm[wid] = sum; sm[4 + wid] = sumsq; }
  __syncthreads();
  sum = sm[0] + sm[1] + sm[2] + sm[3];
  sumsq = sm[4] + sm[5] + sm[6] + sm[7];
  float mean = sum * (1.f / 16384.f);
  float var = sumsq * (1.f / 16384.f) - mean * mean;
  float rstd = rsqrtf(var + 1e-6f);
  if (threadIdx.x < CPG) {
    int c = g * CPG + threadIdx.x;
    float sc = scale[c] * rstd;
    stats[(size_t)b * Cch + c] = make_float2(sc, bias[c] - mean * sc);
  }
}

// ---------------- Tiled GEMMs: fp32 accumulate, mixed-dtype operands ----------
#define TM 128
#define TN 128
#define TK 16
#define LPAD 4  // row stride 132 floats = 528B, 16B-aligned

// Out[b][m][n] = sum_k A[b][k][m] * B[b][k][n]  (both operands k-major)
// GNB: apply per-(b, channel=k) affine from gnstats to B while staging.
// EPI 0: +bias[m], bf16 out.   EPI 1: *C^-0.5, f32 out.
// EPI 2: +bias[m]+resid, f32 out.
template <int EPI, bool GNB, typename TA, typename TB>
__global__ __launch_bounds__(256) void gemm_nn(
    const TA* __restrict__ A, size_t sAb, int sAk,
    const TB* __restrict__ Bm, size_t sBb, int sBk,
    void* __restrict__ Out, size_t sOb, int ldo,
    const float* __restrict__ bias,
    const float* __restrict__ resid, size_t sRb,
    const float2* __restrict__ gnstats, int K) {
  __shared__ float As[TK][TM + LPAD];
  __shared__ float Bs[TK][TN + LPAD];
  const int b = blockIdx.z;
  const int m0 = blockIdx.y * TM, n0 = blockIdx.x * TN;
  const int tid = threadIdx.x;
  const int tx = tid & 15, ty = tid >> 4;
  const int srow = tid >> 4, scol = (tid & 15) * 8;

  const TA* Ap = A + (size_t)b * sAb + (size_t)srow * sAk + m0 + scol;
  const TB* Bp = Bm + (size_t)b * sBb + (size_t)srow * sBk + n0 + scol;

  float acc[8][8];
#pragma unroll
  for (int i = 0; i < 8; ++i)
#pragma unroll
    for (int j = 0; j < 8; ++j) acc[i][j] = 0.f;

  for (int k0 = 0; k0 < K; k0 += TK) {
    alignas(16) float ta[8], tb[8];
    load8(Ap, ta);
    load8(Bp, tb);
    float2 af = make_float2(1.f, 0.f);
    if constexpr (GNB) af = gnstats[(size_t)b * Cch + k0 + srow];
    Ap += (size_t)TK * sAk;
    Bp += (size_t)TK * sBk;
    __syncthreads();
    if constexpr (GNB) {
#pragma unroll
      for (int e = 0; e < 8; ++e) tb[e] = tb[e] * af.x + af.y;
    }
    *(float4*)&As[srow][scol]     = *(const float4*)&ta[0];
    *(float4*)&As[srow][scol + 4] = *(const float4*)&ta[4];
    *(float4*)&Bs[srow][scol]     = *(const float4*)&tb[0];
    *(float4*)&Bs[srow][scol + 4] = *(const float4*)&tb[4];
    __syncthreads();
#pragma unroll
    for (int kk = 0; kk < TK; ++kk) {
      alignas(16) float a[8], bb[8];
      *(float4*)&a[0]  = *(const float4*)&As[kk][ty * 4];
      *(float4*)&a[4]  = *(const float4*)&As[kk][64 + ty * 4];
      *(float4*)&bb[0] = *(const float4*)&Bs[kk][tx * 4];
      *(float4*)&bb[4] = *(const float4*)&Bs[kk][64 + tx * 4];
#pragma unroll
      for (int i = 0; i < 8; ++i)
#pragma unroll
        for (int j = 0; j < 8; ++j) acc[i][j] += a[i] * bb[j];
    }
  }

  if constexpr (EPI == 0) {
    // bf16 out, + bias[m]
    u16* O = (u16*)Out + (size_t)b * sOb;
#pragma unroll
    for (int mi = 0; mi < 2; ++mi)
#pragma unroll
      for (int i = 0; i < 4; ++i) {
        int m = m0 + mi * 64 + ty * 4 + i;
        float bm = bias[m];
        u16* rowp = O + (size_t)m * ldo + n0;
#pragma unroll
        for (int nj = 0; nj < 2; ++nj) {
          union { u16 s[4]; uint2 v2; } pk;
#pragma unroll
          for (int j = 0; j < 4; ++j) pk.s[j] = f2bf(acc[mi * 4 + i][nj * 4 + j] + bm);
          *(uint2*)&rowp[nj * 64 + tx * 4] = pk.v2;
        }
      }
  } else if constexpr (EPI == 1) {
    const float SCALE = 0.044194173824159216f;  // 512^-0.5
    float* O = (float*)Out + (size_t)b * sOb;
#pragma unroll
    for (int mi = 0; mi < 2; ++mi)
#pragma unroll
      for (int i = 0; i < 4; ++i) {
        int m = m0 + mi * 64 + ty * 4 + i;
        float* rowp = O + (size_t)m * ldo + n0;
#pragma unroll
        for (int nj = 0; nj < 2; ++nj) {
          float4 w;
          w.x = acc[mi * 4 + i][nj * 4 + 0] * SCALE;
          w.y = acc[mi * 4 + i][nj * 4 + 1] * SCALE;
          w.z = acc[mi * 4 + i][nj * 4 + 2] * SCALE;
          w.w = acc[mi * 4 + i][nj * 4 + 3] * SCALE;
          *(float4*)&rowp[nj * 64 + tx * 4] = w;
        }
      }
  } else {
    // f32 out, + bias[m] + resid
    float* O = (float*)Out + (size_t)b * sOb;
#pragma unroll
    for (int mi = 0; mi < 2; ++mi)
#pragma unroll
      for (int i = 0; i < 4; ++i) {
        int m = m0 + mi * 64 + ty * 4 + i;
        float bm = bias[m];
        float* rowp = O + (size_t)m * ldo + n0;
        const float* rrow = resid + (size_t)b * sRb + (size_t)m * ldo + n0;
#pragma unroll
        for (int nj = 0; nj < 2; ++nj) {
          float4 rv = *(const float4*)&rrow[nj * 64 + tx * 4];
          float4 w;
          w.x = acc[mi * 4 + i][nj * 4 + 0] + bm + rv.x;
          w.y = acc[mi * 4 + i][nj * 4 + 1] + bm + rv.y;
          w.z = acc[mi * 4 + i][nj * 4 + 2] + bm + rv.z;
          w.w = acc[mi * 4 + i][nj * 4 + 3] + bm + rv.w;
          *(float4*)&rowp[nj * 64 + tx * 4] = w;
        }
      }
  }
}

// Out[b][m][n] = sum_k A[b][m][k] * B[b][n][k]  (both bf16, k-contiguous; PV)
__global__ __launch_bounds__(256) void gemm_nt(
    const u16* __restrict__ A, size_t sAb, int lda,
    const u16* __restrict__ Bm, size_t sBb, int ldb,
    u16* __restrict__ Out, size_t sOb, int ldo, int K) {
  __shared__ float As[TK][TM + LPAD];
  __shared__ float Bs[TK][TN + LPAD];
  const int b = blockIdx.z;
  const int m0 = blockIdx.y * TM, n0 = blockIdx.x * TN;
  const int tid = threadIdx.x;
  const int tx = tid & 15, ty = tid >> 4;
  const int r = tid & 127, kh = (tid >> 7) * 8;

  const u16* Ap = A + (size_t)b * sAb + (size_t)(m0 + r) * lda + kh;
  const u16* Bp = Bm + (size_t)b * sBb + (size_t)(n0 + r) * ldb + kh;

  float acc[8][8];
#pragma unroll
  for (int i = 0; i < 8; ++i)
#pragma unroll
    for (int j = 0; j < 8; ++j) acc[i][j] = 0.f;

  for (int k0 = 0; k0 < K; k0 += TK) {
    uint4 av = *(const uint4*)Ap;
    uint4 bv = *(const uint4*)Bp;
    Ap += TK;
    Bp += TK;
    __syncthreads();
    {
      const u16* pa = (const u16*)&av;
      const u16* pb = (const u16*)&bv;
#pragma unroll
      for (int e = 0; e < 8; ++e) {
        As[kh + e][r] = bf2f(pa[e]);   // transpose-on-stage; lanes r consecutive
        Bs[kh + e][r] = bf2f(pb[e]);
      }
    }
    __syncthreads();
#pragma unroll
    for (int kk = 0; kk < TK; ++kk) {
      alignas(16) float a[8], bb[8];
      *(float4*)&a[0]  = *(const float4*)&As[kk][ty * 4];
      *(float4*)&a[4]  = *(const float4*)&As[kk][64 + ty * 4];
      *(float4*)&bb[0] = *(const float4*)&Bs[kk][tx * 4];
      *(float4*)&bb[4] = *(const float4*)&Bs[kk][64 + tx * 4];
#pragma unroll
      for (int i = 0; i < 8; ++i)
#pragma unroll
        for (int j = 0; j < 8; ++j) acc[i][j] += a[i] * bb[j];
    }
  }

  u16* O = Out + (size_t)b * sOb;
#pragma unroll
  for (int mi = 0; mi < 2; ++mi)
#pragma unroll
    for (int i = 0; i < 4; ++i) {
      int m = m0 + mi * 64 + ty * 4 + i;
      u16* rowp = O + (size_t)m * ldo + n0;
#pragma unroll
      for (int nj = 0; nj < 2; ++nj) {
        union { u16 s[4]; uint2 v2; } pk;
#pragma unroll
        for (int j = 0; j < 4; ++j) pk.s[j] = f2bf(acc[mi * 4 + i][nj * 4 + j]);
        *(uint2*)&rowp[nj * 64 + tx * 4] = pk.v2;
      }
    }
}

// ---------------- Softmax over rows of Sc [nb*S][S]; writes bf16 P in place ----
__global__ __launch_bounds__(256) void softmax_kernel(float* __restrict__ Sc) {
  size_t row = blockIdx.x;
  float* rp = Sc + row * (size_t)Ssp;
  float4 v = ((const float4*)rp)[threadIdx.x];
  float mx = fmaxf(fmaxf(v.x, v.y), fmaxf(v.z, v.w));
#pragma unroll
  for (int off = 32; off > 0; off >>= 1) mx = fmaxf(mx, __shfl_xor(mx, off));
  __shared__ float sm[4];
  __shared__ float sd[4];
  int wid = threadIdx.x >> 6;
  if ((threadIdx.x & 63) == 0) sm[wid] = mx;
  __syncthreads();                 // all row reads complete before any write below
  mx = fmaxf(fmaxf(sm[0], sm[1]), fmaxf(sm[2], sm[3]));
  float e0 = __expf(v.x - mx), e1 = __expf(v.y - mx);
  float e2 = __expf(v.z - mx), e3 = __expf(v.w - mx);
  float s = e0 + e1 + e2 + e3;
#pragma unroll
  for (int off = 32; off > 0; off >>= 1) s += __shfl_xor(s, off);
  if ((threadIdx.x & 63) == 0) sd[wid] = s;
  __syncthreads();
  s = sd[0] + sd[1] + sd[2] + sd[3];
  float inv = 1.f / s;
  union { u16 s4[4]; uint2 v2; } pk;
  pk.s4[0] = f2bf(e0 * inv); pk.s4[1] = f2bf(e1 * inv);
  pk.s4[2] = f2bf(e2 * inv); pk.s4[3] = f2bf(e3 * inv);
  ((uint2*)rp)[threadIdx.x] = pk.v2;  // bf16 P, packed at row start (in place)
}

extern "C" void kernel_launch(void* const* d_in, const int* in_sizes, int n_in,
                              void* d_out, int out_size, void* d_ws, size_t ws_size,
                              hipStream_t stream) {
  (void)in_sizes; (void)n_in; (void)out_size;
  const float* x   = (const float*)d_in[0];
  const float* gns = (const float*)d_in[1];
  const float* gnb = (const float*)d_in[2];
  const float* Wq  = (const float*)d_in[3];
  const float* bq  = (const float*)d_in[4];
  const float* Wk  = (const float*)d_in[5];
  const float* bk  = (const float*)d_in[6];
  const float* Wv  = (const float*)d_in[7];
  const float* bv  = (const float*)d_in[8];
  const float* Wt  = (const float*)d_in[9];
  const float* bt  = (const float*)d_in[10];
  float* out = (float*)d_out;
  char* ws = (char*)d_ws;

  // Workspace layout (ws_size-adaptive; min ~101 MB):
  //   q @ 0MB    (32MB bf16) -> aliased as o during chunked PV (safe: PV chunk
  //                             only overwrites q-batches whose scores are consumed)
  //   k @ 32MB   (32MB bf16)
  //   v @ 64MB   (32MB bf16)
  //   stats @96MB (256KB float2 per (b,c) GN affine)
  //   Sc @ 97MB  (NB*4MB fp32 scores; softmax rewrites rows as bf16 P in place)
  const size_t SZ = (size_t)Bsz * Cch * Ssp * 2;  // 32 MB (bf16 tensor)
  u16* q = (u16*)ws;
  u16* k = (u16*)(ws + SZ);
  u16* v = (u16*)(ws + 2 * SZ);
  float2* stats = (float2*)(ws + 3 * SZ);
  float* Sc = (float*)(ws + (97ull << 20));
  u16* o = q;

  // Chunk count from available workspace (ws_size constant per session -> graph-safe).
  long availMB = (long)(ws_size >> 20) - 97;
  int NB = (int)(availMB / 4);
  if (NB > Bsz) NB = Bsz;
  if (NB < 1) NB = 1;

  const size_t sHB = (size_t)Cch * Ssp;   // per-batch stride of [C][S] tensors (elems)
  const size_t sScB = (size_t)Ssp * Ssp;  // per-batch score stride (fp32 elems)
  dim3 blk(256);

  gnstats_kernel<<<dim3(Bsz * Grp), blk, 0, stream>>>(x, gns, gnb, stats);

  dim3 gp(Ssp / TN, Cch / TM, Bsz);  // [512 x 1024] projection outputs
  gemm_nn<0, true, float, float><<<gp, blk, 0, stream>>>(
      Wq, 0, Cch, x, sHB, Ssp, q, sHB, Ssp, bq, nullptr, 0, stats, Cch);
  gemm_nn<0, true, float, float><<<gp, blk, 0, stream>>>(
      Wk, 0, Cch, x, sHB, Ssp, k, sHB, Ssp, bk, nullptr, 0, stats, Cch);
  gemm_nn<0, true, float, float><<<gp, blk, 0, stream>>>(
      Wv, 0, Cch, x, sHB, Ssp, v, sHB, Ssp, bv, nullptr, 0, stats, Cch);

  for (int b0 = 0; b0 < Bsz; b0 += NB) {
    int nb = (b0 + NB <= Bsz) ? NB : (Bsz - b0);
    dim3 gs(Ssp / TN, Ssp / TM, nb);  // [1024 x 1024] scores per batch
    gemm_nn<1, false, u16, u16><<<gs, blk, 0, stream>>>(
        q + b0 * sHB, sHB, Ssp, k + b0 * sHB, sHB, Ssp,
        Sc, sScB, Ssp, nullptr, nullptr, 0, nullptr, Cch);
    softmax_kernel<<<dim3(nb * Ssp), blk, 0, stream>>>(Sc);
    dim3 go(Ssp / TN, Cch / TM, nb);  // O[b][c][s] = sum_t V[c][t] P[s][t]
    gemm_nt<<<go, blk, 0, stream>>>(
        v + b0 * sHB, sHB, Ssp, (const u16*)Sc, sScB * 2, Ssp * 2,
        o + b0 * sHB, sHB, Ssp, Ssp);
  }

  dim3 gf(Ssp / TN, Cch / TM, Bsz);  // final projection + bias + residual, fp32 out
  gemm_nn<2, false, float, u16><<<gf, blk, 0, stream>>>(
      Wt, 0, Cch, o, sHB, Ssp, out, sHB, Ssp, bt, x, sHB, nullptr, Cch);
}

// Round 4
// 520.240 us; speedup vs baseline: 3.0899x; 3.0899x over previous
//
#include <hip/hip_runtime.h>
#include <stdint.h>

// x [B=32, C=512, H=32, W=32] fp32, 32 groups, S = H*W = 1024. All I/O fp32.
// Internal tensors bf16 (our choice): xt[b][s][c], q_t/k_t[b][s][d], v[b][d][s],
// P[b][s][t] (packed in fp32 score rows), o_t[b][s][c]. All GEMMs run as NT
// (Out[m][n] = sum_k A[m][k]*B[n][k], both operands k-contiguous) on
// mfma_f32_16x16x32_bf16 with the HW-verified layouts:
//   A-frag: A[m=lane&15][k=quad*8+j]   B-frag: B[n=lane&15][k=quad*8+j]
//   C/D:    col=lane&15, row=quad*4+reg
#define Bsz 32
#define Cch 512
#define Ssp 1024
#define Grp 32
#define CPG 16

typedef unsigned short u16;
typedef __attribute__((ext_vector_type(8))) short bf16x8;
typedef __attribute__((ext_vector_type(4))) float f32x4;

__device__ __forceinline__ float bf2f(u16 u) {
  union { float f; uint32_t i; } w; w.i = ((uint32_t)u) << 16; return w.f;
}
__device__ __forceinline__ u16 f2bf(float f) {
  union { float f; uint32_t i; } w; w.f = f;
  uint32_t r = w.i + 0x7fffu + ((w.i >> 16) & 1u);  // RNE
  return (u16)(r >> 16);
}

__device__ __forceinline__ void gload_lds16(const u16* g, u16* l) {
  __builtin_amdgcn_global_load_lds(
      (const __attribute__((address_space(1))) uint32_t*)g,
      (__attribute__((address_space(3))) uint32_t*)l, 16, 0, 0);
}

// ---------------- GN stats: one block per (b,g) -> per-channel affine (A,B) ----
__global__ __launch_bounds__(256) void gnstats_kernel(
    const float* __restrict__ x, const float* __restrict__ scale,
    const float* __restrict__ bias, float2* __restrict__ stats) {
  int b = blockIdx.x >> 5;
  int g = blockIdx.x & 31;
  size_t base = ((size_t)b * Cch + (size_t)g * CPG) * Ssp;
  const float4* xv = (const float4*)(x + base);  // 16384 floats = 4096 float4

  float sum = 0.f, sumsq = 0.f;
#pragma unroll
  for (int it = 0; it < 16; ++it) {
    float4 v = xv[threadIdx.x + 256 * it];
    sum += (v.x + v.y) + (v.z + v.w);
    sumsq += (v.x * v.x + v.y * v.y) + (v.z * v.z + v.w * v.w);
  }
#pragma unroll
  for (int off = 32; off > 0; off >>= 1) {
    sum += __shfl_xor(sum, off);
    sumsq += __shfl_xor(sumsq, off);
  }
  __shared__ float sm[8];
  int wid = threadIdx.x >> 6;
  if ((threadIdx.x & 63) == 0) { sm[wid] = sum; sm[4 + wid] = sumsq; }
  __syncthreads();
  sum = sm[0] + sm[1] + sm[2] + sm[3];
  sumsq = sm[4] + sm[5] + sm[6] + sm[7];
  float mean = sum * (1.f / 16384.f);
  float var = sumsq * (1.f / 16384.f) - mean * mean;
  float rstd = rsqrtf(var + 1e-6f);
  if (threadIdx.x < CPG) {
    int c = g * CPG + threadIdx.x;
    float sc = scale[c] * rstd;
    stats[(size_t)b * Cch + c] = make_float2(sc, bias[c] - mean * sc);
  }
}

// ---------------- x[b][c][s] fp32 -> xt[b][s][c] bf16 with GN affine ----------
__global__ __launch_bounds__(256) void xpose_gn(
    const float* __restrict__ x, const float2* __restrict__ stats,
    u16* __restrict__ xt) {
  __shared__ float T[64][65];
  int b = blockIdx.z;
  int s0 = blockIdx.x * 64, c0 = blockIdx.y * 64;
  int t = threadIdx.x;
  {
    int tx = t & 15, ty = t >> 4;  // tx: 4-float col chunk, ty: row base
    const float* xb = x + ((size_t)b * Cch + c0) * Ssp + s0;
#pragma unroll
    for (int i = 0; i < 4; ++i) {
      int c = ty + 16 * i;
      float2 af = stats[(size_t)b * Cch + c0 + c];
      float4 v = *(const float4*)&xb[(size_t)c * Ssp + tx * 4];
      T[c][tx * 4 + 0] = v.x * af.x + af.y;
      T[c][tx * 4 + 1] = v.y * af.x + af.y;
      T[c][tx * 4 + 2] = v.z * af.x + af.y;
      T[c][tx * 4 + 3] = v.w * af.x + af.y;
    }
  }
  __syncthreads();
  {
    int cx = t & 7, sy = t >> 3;  // cx: 8-elem c chunk, sy: s row
    u16* ob = xt + ((size_t)b * Ssp + s0) * Cch + c0;
#pragma unroll
    for (int i = 0; i < 2; ++i) {
      int s = sy + 32 * i;
      union { u16 h[8]; uint4 v4; } pk;
#pragma unroll
      for (int j = 0; j < 8; ++j) pk.h[j] = f2bf(T[cx * 8 + j][s]);
      *(uint4*)&ob[(size_t)s * Cch + cx * 8] = pk.v4;
    }
  }
}

// ---------------- W[c][d] fp32 (512x512) -> Wt[d][c] bf16, 4 weights ----------
__global__ __launch_bounds__(256) void wxpose(
    const float* __restrict__ w0, const float* __restrict__ w1,
    const float* __restrict__ w2, const float* __restrict__ w3,
    u16* __restrict__ dst) {
  const float* W = blockIdx.z == 0 ? w0 : blockIdx.z == 1 ? w1
                   : blockIdx.z == 2 ? w2 : w3;
  u16* D = dst + (size_t)blockIdx.z * Cch * Cch;
  __shared__ float T[64][65];
  int d0 = blockIdx.x * 64, c0 = blockIdx.y * 64;
  int t = threadIdx.x;
  {
    int tx = t & 15, ty = t >> 4;
#pragma unroll
    for (int i = 0; i < 4; ++i) {
      int c = ty + 16 * i;
      float4 v = *(const float4*)&W[(size_t)(c0 + c) * Cch + d0 + tx * 4];
      T[c][tx * 4 + 0] = v.x; T[c][tx * 4 + 1] = v.y;
      T[c][tx * 4 + 2] = v.z; T[c][tx * 4 + 3] = v.w;
    }
  }
  __syncthreads();
  {
    int cx = t & 7, dy = t >> 3;
#pragma unroll
    for (int i = 0; i < 2; ++i) {
      int d = dy + 32 * i;
      union { u16 h[8]; uint4 v4; } pk;
#pragma unroll
      for (int j = 0; j < 8; ++j) pk.h[j] = f2bf(T[cx * 8 + j][d]);
      *(uint4*)&D[(size_t)(d0 + d) * Cch + c0 + cx * 8] = pk.v4;
    }
  }
}

// ---------------- Unified MFMA NT GEMM: Out[m][n] = sum_k A[m][k] B[n][k] -----
// 128x128 tile, BK=32, 4 waves in 2x2 of 64x64, 4x4 16x16x32 MFMA tiles/wave.
// EPI 0: bf16 out + bias[n]     (q/k projections -> q_t[s][d])
// EPI 1: bf16 out + bias[m]     (v projection -> v[d][s])
// EPI 2: f32 out * C^-0.5       (scores -> Sc[s][s'])
// EPI 3: bf16 out               (PV -> o_t[s][c])
// EPI 4: f32 out + bias[m]+res  (final -> out[d][s])
template <int EPI>
__global__ __launch_bounds__(256) void mfma_nt(
    const u16* __restrict__ A, size_t sAb, int lda,
    const u16* __restrict__ B, size_t sBb, int ldb,
    void* __restrict__ Out, size_t sOb, int ldo,
    const float* __restrict__ bias,
    const float* __restrict__ resid, size_t sRb, int K) {
  __shared__ u16 As[128 * 32];
  __shared__ u16 Bs[128 * 32];
  const int b = blockIdx.z;
  const int m0 = blockIdx.y * 128, n0 = blockIdx.x * 128;
  const int tid = threadIdx.x;
  const int lane = tid & 63, wave = tid >> 6;
  const int wm = wave >> 1, wn = wave & 1;
  const int quad = lane >> 4, l16 = lane & 15;
  const int sr = lane >> 2, sc = (lane & 3) * 8;  // staging: row-in-chunk, elem col

  const u16* Ab = A + (size_t)b * sAb + (size_t)m0 * lda;
  const u16* Bb = B + (size_t)b * sBb + (size_t)n0 * ldb;

  f32x4 acc[4][4] = {};

  for (int k0 = 0; k0 < K; k0 += 32) {
    // Stage A,B tiles [128 rows][32 k] bf16. 8 chunks of 16 rows (1024B) each;
    // wave w stages chunks {2w, 2w+1}. LDS dest = uniform base + lane*16.
#pragma unroll
    for (int i = 0; i < 2; ++i) {
      int c = 2 * wave + i;
      gload_lds16(Ab + (size_t)(16 * c + sr) * lda + k0 + sc, As + c * 512);
      gload_lds16(Bb + (size_t)(16 * c + sr) * ldb + k0 + sc, Bs + c * 512);
    }
    __syncthreads();  // drains vmcnt, publishes LDS
    bf16x8 af[4], bfr[4];
#pragma unroll
    for (int i = 0; i < 4; ++i) {
      af[i]  = *(const bf16x8*)&As[(wm * 64 + i * 16 + l16) * 32 + quad * 8];
      bfr[i] = *(const bf16x8*)&Bs[(wn * 64 + i * 16 + l16) * 32 + quad * 8];
    }
#pragma unroll
    for (int mt = 0; mt < 4; ++mt)
#pragma unroll
      for (int nt = 0; nt < 4; ++nt)
        acc[mt][nt] = __builtin_amdgcn_mfma_f32_16x16x32_bf16(
            af[mt], bfr[nt], acc[mt][nt], 0, 0, 0);
    __syncthreads();  // protect LDS from next iteration's staging
  }

  const float SCALE = 0.044194173824159216f;  // 512^-0.5
#pragma unroll
  for (int mt = 0; mt < 4; ++mt) {
#pragma unroll
    for (int nt = 0; nt < 4; ++nt) {
      int n = n0 + wn * 64 + nt * 16 + l16;
      float bn = 0.f;
      if constexpr (EPI == 0) bn = bias[n];
#pragma unroll
      for (int reg = 0; reg < 4; ++reg) {
        int m = m0 + wm * 64 + mt * 16 + quad * 4 + reg;
        float v = acc[mt][nt][reg];
        size_t idx = (size_t)b * sOb + (size_t)m * ldo + n;
        if constexpr (EPI == 0) {
          ((u16*)Out)[idx] = f2bf(v + bn);
        } else if constexpr (EPI == 1) {
          ((u16*)Out)[idx] = f2bf(v + bias[m]);
        } else if constexpr (EPI == 2) {
          ((float*)Out)[idx] = v * SCALE;
        } else if constexpr (EPI == 3) {
          ((u16*)Out)[idx] = f2bf(v);
        } else {
          ((float*)Out)[idx] = v + bias[m] + resid[(size_t)b * sRb + (size_t)m * ldo + n];
        }
      }
    }
  }
}

// ---------------- Softmax over rows of Sc [nb*S][S]; writes bf16 P in place ----
__global__ __launch_bounds__(256) void softmax_kernel(float* __restrict__ Sc) {
  size_t row = blockIdx.x;
  float* rp = Sc + row * (size_t)Ssp;
  float4 v = ((const float4*)rp)[threadIdx.x];
  float mx = fmaxf(fmaxf(v.x, v.y), fmaxf(v.z, v.w));
#pragma unroll
  for (int off = 32; off > 0; off >>= 1) mx = fmaxf(mx, __shfl_xor(mx, off));
  __shared__ float sm[4];
  __shared__ float sd[4];
  int wid = threadIdx.x >> 6;
  if ((threadIdx.x & 63) == 0) sm[wid] = mx;
  __syncthreads();                 // all row reads complete before any write below
  mx = fmaxf(fmaxf(sm[0], sm[1]), fmaxf(sm[2], sm[3]));
  float e0 = __expf(v.x - mx), e1 = __expf(v.y - mx);
  float e2 = __expf(v.z - mx), e3 = __expf(v.w - mx);
  float s = e0 + e1 + e2 + e3;
#pragma unroll
  for (int off = 32; off > 0; off >>= 1) s += __shfl_xor(s, off);
  if ((threadIdx.x & 63) == 0) sd[wid] = s;
  __syncthreads();
  s = sd[0] + sd[1] + sd[2] + sd[3];
  float inv = 1.f / s;
  union { u16 s4[4]; uint2 v2; } pk;
  pk.s4[0] = f2bf(e0 * inv); pk.s4[1] = f2bf(e1 * inv);
  pk.s4[2] = f2bf(e2 * inv); pk.s4[3] = f2bf(e3 * inv);
  ((uint2*)rp)[threadIdx.x] = pk.v2;  // bf16 P, packed at row start (in place)
}

extern "C" void kernel_launch(void* const* d_in, const int* in_sizes, int n_in,
                              void* d_out, int out_size, void* d_ws, size_t ws_size,
                              hipStream_t stream) {
  (void)in_sizes; (void)n_in; (void)out_size;
  const float* x   = (const float*)d_in[0];
  const float* gns = (const float*)d_in[1];
  const float* gnb = (const float*)d_in[2];
  const float* Wq  = (const float*)d_in[3];
  const float* bq  = (const float*)d_in[4];
  const float* Wk  = (const float*)d_in[5];
  const float* bk  = (const float*)d_in[6];
  const float* Wv  = (const float*)d_in[7];
  const float* bv  = (const float*)d_in[8];
  const float* Wt  = (const float*)d_in[9];
  const float* bt  = (const float*)d_in[10];
  float* out = (float*)d_out;
  char* ws = (char*)d_ws;

  // Workspace (bytes):
  //   q_t @ 0MB   (32MB bf16 [b][s][d]) -> aliased as o_t during chunked PV
  //   k_t @ 32MB  (32MB bf16 [b][s][d])
  //   v   @ 64MB  (32MB bf16 [b][d][s])
  //   W_t @ 96MB  (4 x 0.5MB bf16 [d][c]: q,k,v,t)
  //   stats @98MB (256KB float2)
  //   xt  @ 99MB  (32MB bf16 [b][s][c]) -> dead after projections
  //   Sc  @ 131MB if it fits (NB=32), else aliases xt @99MB (NB=8)
  const size_t SZ = (size_t)Bsz * Cch * Ssp * 2;  // 32 MB
  u16* qt  = (u16*)ws;
  u16* kt  = (u16*)(ws + SZ);
  u16* vv  = (u16*)(ws + 2 * SZ);
  u16* Wts = (u16*)(ws + (96ull << 20));
  float2* stats = (float2*)(ws + (98ull << 20));
  u16* xt  = (u16*)(ws + (99ull << 20));
  u16* ot  = qt;

  float* Sc;
  int NB;
  if (ws_size >= (259ull << 20)) { Sc = (float*)(ws + (131ull << 20)); NB = 32; }
  else                           { Sc = (float*)xt;                    NB = 8;  }

  const size_t WSZ = (size_t)Cch * Cch;  // per-weight elems
  u16* Wqt = Wts;
  u16* Wkt = Wts + WSZ;
  u16* Wvt = Wts + 2 * WSZ;
  u16* Wtt = Wts + 3 * WSZ;

  const size_t sSC = (size_t)Ssp * Cch;   // 1024*512: q_t/xt/o_t per-batch elems
  const size_t sCS = (size_t)Cch * Ssp;   // v / x / out per-batch elems
  const size_t sScB = (size_t)Ssp * Ssp;  // score per-batch fp32 elems
  dim3 blk(256);

  gnstats_kernel<<<dim3(Bsz * Grp), blk, 0, stream>>>(x, gns, gnb, stats);
  xpose_gn<<<dim3(Ssp / 64, Cch / 64, Bsz), blk, 0, stream>>>(x, stats, xt);
  wxpose<<<dim3(8, 8, 4), blk, 0, stream>>>(Wq, Wk, Wv, Wt, Wts);

  // q/k: m=s(1024), n=d(512), k=c(512): A=xt, B=W_t -> q_t[s][d] + bias[n]
  mfma_nt<0><<<dim3(4, 8, Bsz), blk, 0, stream>>>(
      xt, sSC, Cch, Wqt, 0, Cch, qt, sSC, Cch, bq, nullptr, 0, Cch);
  mfma_nt<0><<<dim3(4, 8, Bsz), blk, 0, stream>>>(
      xt, sSC, Cch, Wkt, 0, Cch, kt, sSC, Cch, bk, nullptr, 0, Cch);
  // v: m=d(512), n=s(1024), k=c(512): A=Wv_t, B=xt -> v[d][s] + bias[m]
  mfma_nt<1><<<dim3(8, 4, Bsz), blk, 0, stream>>>(
      Wvt, 0, Cch, xt, sSC, Cch, vv, sCS, Ssp, bv, nullptr, 0, Cch);

  for (int b0 = 0; b0 < Bsz; b0 += NB) {
    int nb = (b0 + NB <= Bsz) ? NB : (Bsz - b0);
    // scores: m=s, n=s', k=d: A=q_t, B=k_t -> Sc fp32 * C^-0.5
    mfma_nt<2><<<dim3(8, 8, nb), blk, 0, stream>>>(
        qt + b0 * sSC, sSC, Cch, kt + b0 * sSC, sSC, Cch,
        Sc, sScB, Ssp, nullptr, nullptr, 0, Cch);
    softmax_kernel<<<dim3(nb * Ssp), blk, 0, stream>>>(Sc);
    // PV: m=s(1024), n=c(512), k=t(1024): A=P (ld 2048 u16), B=v -> o_t[s][c]
    mfma_nt<3><<<dim3(4, 8, nb), blk, 0, stream>>>(
        (const u16*)Sc, sScB * 2, Ssp * 2, vv + b0 * sCS, sCS, Ssp,
        ot + b0 * sSC, sSC, Cch, nullptr, nullptr, 0, Ssp);
  }

  // final: m=d(512), n=s(1024), k=c(512): A=Wt_t, B=o_t -> fp32 +bias[m]+x
  mfma_nt<4><<<dim3(8, 4, Bsz), blk, 0, stream>>>(
      Wtt, 0, Cch, ot, sSC, Cch, out, sCS, Ssp, bt, x, sCS, Cch);
}

// Round 5
// 473.832 us; speedup vs baseline: 3.3925x; 1.0979x over previous
//
#include <hip/hip_runtime.h>
#include <stdint.h>

// x [B=32, C=512, H=32, W=32] fp32, 32 groups, S = H*W = 1024. All I/O fp32.
// Internal tensors bf16 (our choice): xt[b][s][c], q_t/k_t[b][s][d], v[b][d][s],
// P[b][s][t] (packed in fp32 score rows), o_t[b][s][c]. All GEMMs run as NT
// (Out[m][n] = sum_k A[m][k]*B[n][k], both operands k-contiguous) on
// mfma_f32_16x16x32_bf16 with the HW-verified layouts:
//   A-frag: A[m=lane&15][k=quad*8+j]   B-frag: B[n=lane&15][k=quad*8+j]
//   C/D:    col=lane&15, row=quad*4+reg
// R5: BK=64 (128B LDS rows = 32 banks) + XOR chunk swizzle by (row&7) ->
// quarter-wave fragment reads hit all 32 banks (was 8 -> 4.0 extra cyc/read,
// SQ_LDS_BANK_CONFLICT=2^21). Barriers halved (32 MFMA per pair).
#define Bsz 32
#define Cch 512
#define Ssp 1024
#define Grp 32
#define CPG 16

typedef unsigned short u16;
typedef __attribute__((ext_vector_type(8))) short bf16x8;
typedef __attribute__((ext_vector_type(4))) float f32x4;

__device__ __forceinline__ float bf2f(u16 u) {
  union { float f; uint32_t i; } w; w.i = ((uint32_t)u) << 16; return w.f;
}
__device__ __forceinline__ u16 f2bf(float f) {
  union { float f; uint32_t i; } w; w.f = f;
  uint32_t r = w.i + 0x7fffu + ((w.i >> 16) & 1u);  // RNE
  return (u16)(r >> 16);
}

__device__ __forceinline__ void gload_lds16(const u16* g, u16* l) {
  __builtin_amdgcn_global_load_lds(
      (const __attribute__((address_space(1))) uint32_t*)g,
      (__attribute__((address_space(3))) uint32_t*)l, 16, 0, 0);
}

// ---------------- GN stats: one block per (b,g) -> per-channel affine (A,B) ----
__global__ __launch_bounds__(256) void gnstats_kernel(
    const float* __restrict__ x, const float* __restrict__ scale,
    const float* __restrict__ bias, float2* __restrict__ stats) {
  int b = blockIdx.x >> 5;
  int g = blockIdx.x & 31;
  size_t base = ((size_t)b * Cch + (size_t)g * CPG) * Ssp;
  const float4* xv = (const float4*)(x + base);  // 16384 floats = 4096 float4

  float sum = 0.f, sumsq = 0.f;
#pragma unroll
  for (int it = 0; it < 16; ++it) {
    float4 v = xv[threadIdx.x + 256 * it];
    sum += (v.x + v.y) + (v.z + v.w);
    sumsq += (v.x * v.x + v.y * v.y) + (v.z * v.z + v.w * v.w);
  }
#pragma unroll
  for (int off = 32; off > 0; off >>= 1) {
    sum += __shfl_xor(sum, off);
    sumsq += __shfl_xor(sumsq, off);
  }
  __shared__ float sm[8];
  int wid = threadIdx.x >> 6;
  if ((threadIdx.x & 63) == 0) { sm[wid] = sum; sm[4 + wid] = sumsq; }
  __syncthreads();
  sum = sm[0] + sm[1] + sm[2] + sm[3];
  sumsq = sm[4] + sm[5] + sm[6] + sm[7];
  float mean = sum * (1.f / 16384.f);
  float var = sumsq * (1.f / 16384.f) - mean * mean;
  float rstd = rsqrtf(var + 1e-6f);
  if (threadIdx.x < CPG) {
    int c = g * CPG + threadIdx.x;
    float sc = scale[c] * rstd;
    stats[(size_t)b * Cch + c] = make_float2(sc, bias[c] - mean * sc);
  }
}

// ---------------- x[b][c][s] fp32 -> xt[b][s][c] bf16 with GN affine ----------
__global__ __launch_bounds__(256) void xpose_gn(
    const float* __restrict__ x, const float2* __restrict__ stats,
    u16* __restrict__ xt) {
  __shared__ float T[64][65];
  int b = blockIdx.z;
  int s0 = blockIdx.x * 64, c0 = blockIdx.y * 64;
  int t = threadIdx.x;
  {
    int tx = t & 15, ty = t >> 4;  // tx: 4-float col chunk, ty: row base
    const float* xb = x + ((size_t)b * Cch + c0) * Ssp + s0;
#pragma unroll
    for (int i = 0; i < 4; ++i) {
      int c = ty + 16 * i;
      float2 af = stats[(size_t)b * Cch + c0 + c];
      float4 v = *(const float4*)&xb[(size_t)c * Ssp + tx * 4];
      T[c][tx * 4 + 0] = v.x * af.x + af.y;
      T[c][tx * 4 + 1] = v.y * af.x + af.y;
      T[c][tx * 4 + 2] = v.z * af.x + af.y;
      T[c][tx * 4 + 3] = v.w * af.x + af.y;
    }
  }
  __syncthreads();
  {
    int cx = t & 7, sy = t >> 3;  // cx: 8-elem c chunk, sy: s row
    u16* ob = xt + ((size_t)b * Ssp + s0) * Cch + c0;
#pragma unroll
    for (int i = 0; i < 2; ++i) {
      int s = sy + 32 * i;
      union { u16 h[8]; uint4 v4; } pk;
#pragma unroll
      for (int j = 0; j < 8; ++j) pk.h[j] = f2bf(T[cx * 8 + j][s]);
      *(uint4*)&ob[(size_t)s * Cch + cx * 8] = pk.v4;
    }
  }
}

// ---------------- W[c][d] fp32 (512x512) -> Wt[d][c] bf16, 4 weights ----------
__global__ __launch_bounds__(256) void wxpose(
    const float* __restrict__ w0, const float* __restrict__ w1,
    const float* __restrict__ w2, const float* __restrict__ w3,
    u16* __restrict__ dst) {
  const float* W = blockIdx.z == 0 ? w0 : blockIdx.z == 1 ? w1
                   : blockIdx.z == 2 ? w2 : w3;
  u16* D = dst + (size_t)blockIdx.z * Cch * Cch;
  __shared__ float T[64][65];
  int d0 = blockIdx.x * 64, c0 = blockIdx.y * 64;
  int t = threadIdx.x;
  {
    int tx = t & 15, ty = t >> 4;
#pragma unroll
    for (int i = 0; i < 4; ++i) {
      int c = ty + 16 * i;
      float4 v = *(const float4*)&W[(size_t)(c0 + c) * Cch + d0 + tx * 4];
      T[c][tx * 4 + 0] = v.x; T[c][tx * 4 + 1] = v.y;
      T[c][tx * 4 + 2] = v.z; T[c][tx * 4 + 3] = v.w;
    }
  }
  __syncthreads();
  {
    int cx = t & 7, dy = t >> 3;
#pragma unroll
    for (int i = 0; i < 2; ++i) {
      int d = dy + 32 * i;
      union { u16 h[8]; uint4 v4; } pk;
#pragma unroll
      for (int j = 0; j < 8; ++j) pk.h[j] = f2bf(T[cx * 8 + j][d]);
      *(uint4*)&D[(size_t)(d0 + d) * Cch + c0 + cx * 8] = pk.v4;
    }
  }
}

// ---------------- Unified MFMA NT GEMM: Out[m][n] = sum_k A[m][k] B[n][k] -----
// 128x128 tile, BK=64, 4 waves in 2x2 of 64x64, 4x4 16x16x32 MFMA tiles/wave.
// LDS tile [128 rows][64 k] u16; row = 128 B = 8 chunks of 16 B; physical chunk
// p of row r holds logical k-chunk p^(r&7) (XOR swizzle, conflict-free reads).
// EPI 0: bf16 out + bias[n]     (q/k projections -> q_t[s][d])
// EPI 1: bf16 out + bias[m]     (v projection -> v[d][s])
// EPI 2: f32 out * C^-0.5       (scores -> Sc[s][s'])
// EPI 3: bf16 out               (PV -> o_t[s][c])
// EPI 4: f32 out + bias[m]+res  (final -> out[d][s])
template <int EPI>
__global__ __launch_bounds__(256) void mfma_nt(
    const u16* __restrict__ A, size_t sAb, int lda,
    const u16* __restrict__ B, size_t sBb, int ldb,
    void* __restrict__ Out, size_t sOb, int ldo,
    const float* __restrict__ bias,
    const float* __restrict__ resid, size_t sRb, int K) {
  __shared__ u16 As[128 * 64];
  __shared__ u16 Bs[128 * 64];
  const int b = blockIdx.z;
  const int m0 = blockIdx.y * 128, n0 = blockIdx.x * 128;
  const int tid = threadIdx.x;
  const int lane = tid & 63, wave = tid >> 6;
  const int wm = wave >> 1, wn = wave & 1;
  const int quad = lane >> 4, l16 = lane & 15;
  const int rseg = lane >> 3;   // row within an 8-row (1 KB) staging segment
  const int pchunk = lane & 7;  // physical 16B chunk this lane fills

  const u16* Ab = A + (size_t)b * sAb + (size_t)m0 * lda;
  const u16* Bb = B + (size_t)b * sBb + (size_t)n0 * ldb;

  f32x4 acc[4][4] = {};

  for (int k0 = 0; k0 < K; k0 += 64) {
    // Stage A,B tiles [128][64] u16 = 16 KB each. 16 segments of 8 rows (1 KB);
    // wave w stages segments 4w..4w+3. LDS dest = uniform base + lane*16;
    // lane fetches the XOR-permuted logical chunk of its row.
#pragma unroll
    for (int i = 0; i < 4; ++i) {
      int seg = 4 * wave + i;
      int r = seg * 8 + rseg;
      int ck = (pchunk ^ (r & 7)) * 8;  // logical k-offset (u16 elems)
      gload_lds16(Ab + (size_t)r * lda + k0 + ck, As + seg * 512);
      gload_lds16(Bb + (size_t)r * ldb + k0 + ck, Bs + seg * 512);
    }
    __syncthreads();  // drains vmcnt, publishes LDS
#pragma unroll
    for (int ks = 0; ks < 2; ++ks) {
      bf16x8 af[4], bfr[4];
#pragma unroll
      for (int i = 0; i < 4; ++i) {
        int ra = wm * 64 + i * 16 + l16;
        af[i]  = *(const bf16x8*)&As[ra * 64 + (((ks * 4 + quad) ^ (ra & 7)) << 3)];
        int rb = wn * 64 + i * 16 + l16;
        bfr[i] = *(const bf16x8*)&Bs[rb * 64 + (((ks * 4 + quad) ^ (rb & 7)) << 3)];
      }
#pragma unroll
      for (int mt = 0; mt < 4; ++mt)
#pragma unroll
        for (int nt = 0; nt < 4; ++nt)
          acc[mt][nt] = __builtin_amdgcn_mfma_f32_16x16x32_bf16(
              af[mt], bfr[nt], acc[mt][nt], 0, 0, 0);
    }
    __syncthreads();  // protect LDS from next iteration's staging
  }

  const float SCALE = 0.044194173824159216f;  // 512^-0.5
#pragma unroll
  for (int mt = 0; mt < 4; ++mt) {
#pragma unroll
    for (int nt = 0; nt < 4; ++nt) {
      int n = n0 + wn * 64 + nt * 16 + l16;
      float bn = 0.f;
      if constexpr (EPI == 0) bn = bias[n];
#pragma unroll
      for (int reg = 0; reg < 4; ++reg) {
        int m = m0 + wm * 64 + mt * 16 + quad * 4 + reg;
        float v = acc[mt][nt][reg];
        size_t idx = (size_t)b * sOb + (size_t)m * ldo + n;
        if constexpr (EPI == 0) {
          ((u16*)Out)[idx] = f2bf(v + bn);
        } else if constexpr (EPI == 1) {
          ((u16*)Out)[idx] = f2bf(v + bias[m]);
        } else if constexpr (EPI == 2) {
          ((float*)Out)[idx] = v * SCALE;
        } else if constexpr (EPI == 3) {
          ((u16*)Out)[idx] = f2bf(v);
        } else {
          ((float*)Out)[idx] = v + bias[m] + resid[(size_t)b * sRb + (size_t)m * ldo + n];
        }
      }
    }
  }
}

// ---------------- Softmax over rows of Sc [nb*S][S]; writes bf16 P in place ----
__global__ __launch_bounds__(256) void softmax_kernel(float* __restrict__ Sc) {
  size_t row = blockIdx.x;
  float* rp = Sc + row * (size_t)Ssp;
  float4 v = ((const float4*)rp)[threadIdx.x];
  float mx = fmaxf(fmaxf(v.x, v.y), fmaxf(v.z, v.w));
#pragma unroll
  for (int off = 32; off > 0; off >>= 1) mx = fmaxf(mx, __shfl_xor(mx, off));
  __shared__ float sm[4];
  __shared__ float sd[4];
  int wid = threadIdx.x >> 6;
  if ((threadIdx.x & 63) == 0) sm[wid] = mx;
  __syncthreads();                 // all row reads complete before any write below
  mx = fmaxf(fmaxf(sm[0], sm[1]), fmaxf(sm[2], sm[3]));
  float e0 = __expf(v.x - mx), e1 = __expf(v.y - mx);
  float e2 = __expf(v.z - mx), e3 = __expf(v.w - mx);
  float s = e0 + e1 + e2 + e3;
#pragma unroll
  for (int off = 32; off > 0; off >>= 1) s += __shfl_xor(s, off);
  if ((threadIdx.x & 63) == 0) sd[wid] = s;
  __syncthreads();
  s = sd[0] + sd[1] + sd[2] + sd[3];
  float inv = 1.f / s;
  union { u16 s4[4]; uint2 v2; } pk;
  pk.s4[0] = f2bf(e0 * inv); pk.s4[1] = f2bf(e1 * inv);
  pk.s4[2] = f2bf(e2 * inv); pk.s4[3] = f2bf(e3 * inv);
  ((uint2*)rp)[threadIdx.x] = pk.v2;  // bf16 P, packed at row start (in place)
}

extern "C" void kernel_launch(void* const* d_in, const int* in_sizes, int n_in,
                              void* d_out, int out_size, void* d_ws, size_t ws_size,
                              hipStream_t stream) {
  (void)in_sizes; (void)n_in; (void)out_size;
  const float* x   = (const float*)d_in[0];
  const float* gns = (const float*)d_in[1];
  const float* gnb = (const float*)d_in[2];
  const float* Wq  = (const float*)d_in[3];
  const float* bq  = (const float*)d_in[4];
  const float* Wk  = (const float*)d_in[5];
  const float* bk  = (const float*)d_in[6];
  const float* Wv  = (const float*)d_in[7];
  const float* bv  = (const float*)d_in[8];
  const float* Wt  = (const float*)d_in[9];
  const float* bt  = (const float*)d_in[10];
  float* out = (float*)d_out;
  char* ws = (char*)d_ws;

  // Workspace (bytes):
  //   q_t @ 0MB   (32MB bf16 [b][s][d]) -> aliased as o_t during chunked PV
  //   k_t @ 32MB  (32MB bf16 [b][s][d])
  //   v   @ 64MB  (32MB bf16 [b][d][s])
  //   W_t @ 96MB  (4 x 0.5MB bf16 [d][c]: q,k,v,t)
  //   stats @98MB (256KB float2)
  //   xt  @ 99MB  (32MB bf16 [b][s][c]) -> dead after projections
  //   Sc  @ 131MB if it fits (NB=32), else aliases xt @99MB (NB=8)
  const size_t SZ = (size_t)Bsz * Cch * Ssp * 2;  // 32 MB
  u16* qt  = (u16*)ws;
  u16* kt  = (u16*)(ws + SZ);
  u16* vv  = (u16*)(ws + 2 * SZ);
  u16* Wts = (u16*)(ws + (96ull << 20));
  float2* stats = (float2*)(ws + (98ull << 20));
  u16* xt  = (u16*)(ws + (99ull << 20));
  u16* ot  = qt;

  float* Sc;
  int NB;
  if (ws_size >= (259ull << 20)) { Sc = (float*)(ws + (131ull << 20)); NB = 32; }
  else                           { Sc = (float*)xt;                    NB = 8;  }

  const size_t WSZ = (size_t)Cch * Cch;  // per-weight elems
  u16* Wqt = Wts;
  u16* Wkt = Wts + WSZ;
  u16* Wvt = Wts + 2 * WSZ;
  u16* Wtt = Wts + 3 * WSZ;

  const size_t sSC = (size_t)Ssp * Cch;   // 1024*512: q_t/xt/o_t per-batch elems
  const size_t sCS = (size_t)Cch * Ssp;   // v / x / out per-batch elems
  const size_t sScB = (size_t)Ssp * Ssp;  // score per-batch fp32 elems
  dim3 blk(256);

  gnstats_kernel<<<dim3(Bsz * Grp), blk, 0, stream>>>(x, gns, gnb, stats);
  xpose_gn<<<dim3(Ssp / 64, Cch / 64, Bsz), blk, 0, stream>>>(x, stats, xt);
  wxpose<<<dim3(8, 8, 4), blk, 0, stream>>>(Wq, Wk, Wv, Wt, Wts);

  // q/k: m=s(1024), n=d(512), k=c(512): A=xt, B=W_t -> q_t[s][d] + bias[n]
  mfma_nt<0><<<dim3(4, 8, Bsz), blk, 0, stream>>>(
      xt, sSC, Cch, Wqt, 0, Cch, qt, sSC, Cch, bq, nullptr, 0, Cch);
  mfma_nt<0><<<dim3(4, 8, Bsz), blk, 0, stream>>>(
      xt, sSC, Cch, Wkt, 0, Cch, kt, sSC, Cch, bk, nullptr, 0, Cch);
  // v: m=d(512), n=s(1024), k=c(512): A=Wv_t, B=xt -> v[d][s] + bias[m]
  mfma_nt<1><<<dim3(8, 4, Bsz), blk, 0, stream>>>(
      Wvt, 0, Cch, xt, sSC, Cch, vv, sCS, Ssp, bv, nullptr, 0, Cch);

  for (int b0 = 0; b0 < Bsz; b0 += NB) {
    int nb = (b0 + NB <= Bsz) ? NB : (Bsz - b0);
    // scores: m=s, n=s', k=d: A=q_t, B=k_t -> Sc fp32 * C^-0.5
    mfma_nt<2><<<dim3(8, 8, nb), blk, 0, stream>>>(
        qt + b0 * sSC, sSC, Cch, kt + b0 * sSC, sSC, Cch,
        Sc, sScB, Ssp, nullptr, nullptr, 0, Cch);
    softmax_kernel<<<dim3(nb * Ssp), blk, 0, stream>>>(Sc);
    // PV: m=s(1024), n=c(512), k=t(1024): A=P (ld 2048 u16), B=v -> o_t[s][c]
    mfma_nt<3><<<dim3(4, 8, nb), blk, 0, stream>>>(
        (const u16*)Sc, sScB * 2, Ssp * 2, vv + b0 * sCS, sCS, Ssp,
        ot + b0 * sSC, sSC, Cch, nullptr, nullptr, 0, Ssp);
  }

  // final: m=d(512), n=s(1024), k=c(512): A=Wt_t, B=o_t -> fp32 +bias[m]+x
  mfma_nt<4><<<dim3(8, 4, Bsz), blk, 0, stream>>>(
      Wtt, 0, Cch, ot, sSC, Cch, out, sCS, Ssp, bt, x, sCS, Cch);
}

// Round 6
// 413.509 us; speedup vs baseline: 3.8874x; 1.1459x over previous
//
#include <hip/hip_runtime.h>
#include <stdint.h>

// x [B=32, C=512, H=32, W=32] fp32, 32 groups, S = H*W = 1024. All I/O fp32.
// Internal tensors bf16: xt[b][s][c], qkt[b][s][1024] (q|k fused), v[b][d][s],
// Sc/P[b][s][t] bf16, o_t[b][s][c]. All GEMMs NT (Out[m][n] = sum_k A[m][k]B[n][k])
// on mfma_f32_16x16x32_bf16:
//   A-frag: A[m=lane&15][k=quad*8+j]  B-frag: B[n=lane&15][k=quad*8+j]
//   C/D:    col=lane&15, row=quad*4+reg
// R6: double-buffered BK=32 K-loop (stage next while MFMA current, 1 barrier/iter),
// row-pair XOR swizzle (LDS line = rows {2q,2q+1}, chunks ^ (q&7), 2-way max = free),
// bf16 scores, fused q+k projection.
#define Bsz 32
#define Cch 512
#define Ssp 1024
#define Grp 32
#define CPG 16

typedef unsigned short u16;
typedef __attribute__((ext_vector_type(8))) short bf16x8;
typedef __attribute__((ext_vector_type(4))) float f32x4;

__device__ __forceinline__ float bf2f(u16 u) {
  union { float f; uint32_t i; } w; w.i = ((uint32_t)u) << 16; return w.f;
}
__device__ __forceinline__ u16 f2bf(float f) {
  union { float f; uint32_t i; } w; w.f = f;
  uint32_t r = w.i + 0x7fffu + ((w.i >> 16) & 1u);  // RNE
  return (u16)(r >> 16);
}

__device__ __forceinline__ void gload_lds16(const u16* g, u16* l) {
  __builtin_amdgcn_global_load_lds(
      (const __attribute__((address_space(1))) uint32_t*)g,
      (__attribute__((address_space(3))) uint32_t*)l, 16, 0, 0);
}

// ---------------- GN stats: one block per (b,g) -> per-channel affine (A,B) ----
__global__ __launch_bounds__(256) void gnstats_kernel(
    const float* __restrict__ x, const float* __restrict__ scale,
    const float* __restrict__ bias, float2* __restrict__ stats) {
  int b = blockIdx.x >> 5;
  int g = blockIdx.x & 31;
  size_t base = ((size_t)b * Cch + (size_t)g * CPG) * Ssp;
  const float4* xv = (const float4*)(x + base);

  float sum = 0.f, sumsq = 0.f;
#pragma unroll
  for (int it = 0; it < 16; ++it) {
    float4 v = xv[threadIdx.x + 256 * it];
    sum += (v.x + v.y) + (v.z + v.w);
    sumsq += (v.x * v.x + v.y * v.y) + (v.z * v.z + v.w * v.w);
  }
#pragma unroll
  for (int off = 32; off > 0; off >>= 1) {
    sum += __shfl_xor(sum, off);
    sumsq += __shfl_xor(sumsq, off);
  }
  __shared__ float sm[8];
  int wid = threadIdx.x >> 6;
  if ((threadIdx.x & 63) == 0) { sm[wid] = sum; sm[4 + wid] = sumsq; }
  __syncthreads();
  sum = sm[0] + sm[1] + sm[2] + sm[3];
  sumsq = sm[4] + sm[5] + sm[6] + sm[7];
  float mean = sum * (1.f / 16384.f);
  float var = sumsq * (1.f / 16384.f) - mean * mean;
  float rstd = rsqrtf(var + 1e-6f);
  if (threadIdx.x < CPG) {
    int c = g * CPG + threadIdx.x;
    float sc = scale[c] * rstd;
    stats[(size_t)b * Cch + c] = make_float2(sc, bias[c] - mean * sc);
  }
}

// ---------------- x[b][c][s] fp32 -> xt[b][s][c] bf16 with GN affine ----------
__global__ __launch_bounds__(256) void xpose_gn(
    const float* __restrict__ x, const float2* __restrict__ stats,
    u16* __restrict__ xt) {
  __shared__ float T[64][65];
  int b = blockIdx.z;
  int s0 = blockIdx.x * 64, c0 = blockIdx.y * 64;
  int t = threadIdx.x;
  {
    int tx = t & 15, ty = t >> 4;
    const float* xb = x + ((size_t)b * Cch + c0) * Ssp + s0;
#pragma unroll
    for (int i = 0; i < 4; ++i) {
      int c = ty + 16 * i;
      float2 af = stats[(size_t)b * Cch + c0 + c];
      float4 v = *(const float4*)&xb[(size_t)c * Ssp + tx * 4];
      T[c][tx * 4 + 0] = v.x * af.x + af.y;
      T[c][tx * 4 + 1] = v.y * af.x + af.y;
      T[c][tx * 4 + 2] = v.z * af.x + af.y;
      T[c][tx * 4 + 3] = v.w * af.x + af.y;
    }
  }
  __syncthreads();
  {
    int cx = t & 7, sy = t >> 3;
    u16* ob = xt + ((size_t)b * Ssp + s0) * Cch + c0;
#pragma unroll
    for (int i = 0; i < 2; ++i) {
      int s = sy + 32 * i;
      union { u16 h[8]; uint4 v4; } pk;
#pragma unroll
      for (int j = 0; j < 8; ++j) pk.h[j] = f2bf(T[cx * 8 + j][s]);
      *(uint4*)&ob[(size_t)s * Cch + cx * 8] = pk.v4;
    }
  }
}

// ---------------- W[c][d] fp32 (512x512) -> Wt[d][c] bf16, 4 weights ----------
__global__ __launch_bounds__(256) void wxpose(
    const float* __restrict__ w0, const float* __restrict__ w1,
    const float* __restrict__ w2, const float* __restrict__ w3,
    u16* __restrict__ dst) {
  const float* W = blockIdx.z == 0 ? w0 : blockIdx.z == 1 ? w1
                   : blockIdx.z == 2 ? w2 : w3;
  u16* D = dst + (size_t)blockIdx.z * Cch * Cch;
  __shared__ float T[64][65];
  int d0 = blockIdx.x * 64, c0 = blockIdx.y * 64;
  int t = threadIdx.x;
  {
    int tx = t & 15, ty = t >> 4;
#pragma unroll
    for (int i = 0; i < 4; ++i) {
      int c = ty + 16 * i;
      float4 v = *(const float4*)&W[(size_t)(c0 + c) * Cch + d0 + tx * 4];
      T[c][tx * 4 + 0] = v.x; T[c][tx * 4 + 1] = v.y;
      T[c][tx * 4 + 2] = v.z; T[c][tx * 4 + 3] = v.w;
    }
  }
  __syncthreads();
  {
    int cx = t & 7, dy = t >> 3;
#pragma unroll
    for (int i = 0; i < 2; ++i) {
      int d = dy + 32 * i;
      union { u16 h[8]; uint4 v4; } pk;
#pragma unroll
      for (int j = 0; j < 8; ++j) pk.h[j] = f2bf(T[cx * 8 + j][d]);
      *(uint4*)&D[(size_t)(d0 + d) * Cch + c0 + cx * 8] = pk.v4;
    }
  }
}

// ---------------- Unified MFMA NT GEMM, double-buffered BK=32 -----------------
// 128x128 tile, 4 waves in 2x2 of 64x64, 4x4 16x16x32 MFMA tiles/wave.
// LDS per op-buffer: [64 pair-lines][128B]; line q holds rows {2q,2q+1} as 8
// 16B chunks; physical chunk p stores logical chunk p^(q&7) where logical
// c = half*4 + kchunk (half = row&1, kchunk = k/8). Reads: 2 lanes/bank-group.
// EPI 0: bf16 out + bias (n<512: bq[n], else bk[n-512])   (fused q|k proj)
// EPI 1: bf16 out + bias[m]                               (v proj -> v[d][s])
// EPI 2: bf16 out * C^-0.5                                (scores -> Sc bf16)
// EPI 3: bf16 out                                         (PV -> o_t[s][c])
// EPI 4: f32 out + bias[m] + resid                        (final -> out[d][s])
template <int EPI>
__global__ __launch_bounds__(256) void mfma_nt(
    const u16* __restrict__ A, size_t sAb, int lda,
    const u16* __restrict__ B, size_t sBb, int ldb,
    void* __restrict__ Out, size_t sOb, int ldo,
    const float* __restrict__ bias,
    const float* __restrict__ bias2_or_resid, size_t sRb, int K) {
  __shared__ u16 As[2 * 4096];
  __shared__ u16 Bs[2 * 4096];
  const int b = blockIdx.z;
  const int m0 = blockIdx.y * 128, n0 = blockIdx.x * 128;
  const int tid = threadIdx.x;
  const int lane = tid & 63, wave = tid >> 6;
  const int wm = wave >> 1, wn = wave & 1;
  const int quad = lane >> 4, l16 = lane & 15;

  // Staging decode (per lane): physical chunk p = lane&7 of pair qq = lane>>3
  // within its 16-row segment; logical c = p ^ qq -> row 2*qq + (c>>2),
  // k-offset (c&3)*8.
  const int sp = lane & 7, sq = lane >> 3;
  const int scl = sp ^ sq;
  const int srow = 2 * sq + (scl >> 2);
  const int scol = (scl & 3) * 8;

  const u16* Ab = A + (size_t)b * sAb + (size_t)m0 * lda;
  const u16* Bb = B + (size_t)b * sBb + (size_t)n0 * ldb;

  f32x4 acc[4][4] = {};

  // stage(buf, k): 8 segments of 16 rows per operand; wave stages 2 each.
#define STAGE(bufidx, kk)                                                      \
  {                                                                            \
    _Pragma("unroll") for (int i = 0; i < 2; ++i) {                            \
      int seg = 2 * wave + i;                                                  \
      gload_lds16(Ab + (size_t)(16 * seg + srow) * lda + (kk) + scol,          \
                  As + (bufidx) * 4096 + seg * 512);                           \
      gload_lds16(Bb + (size_t)(16 * seg + srow) * ldb + (kk) + scol,          \
                  Bs + (bufidx) * 4096 + seg * 512);                           \
    }                                                                          \
  }

  STAGE(0, 0)
  __syncthreads();
  int cur = 0;
  for (int k0 = 0; k0 < K; k0 += 32) {
    if (k0 + 32 < K) STAGE(cur ^ 1, k0 + 32)
    bf16x8 af[4], bfr[4];
#pragma unroll
    for (int i = 0; i < 4; ++i) {
      int ra = wm * 64 + i * 16 + l16;
      int qa = ra >> 1, ca = ((ra & 1) << 2) + quad;
      af[i] = *(const bf16x8*)&As[cur * 4096 + qa * 64 + (ca ^ (qa & 7)) * 8];
      int rb = wn * 64 + i * 16 + l16;
      int qb = rb >> 1, cb = ((rb & 1) << 2) + quad;
      bfr[i] = *(const bf16x8*)&Bs[cur * 4096 + qb * 64 + (cb ^ (qb & 7)) * 8];
    }
#pragma unroll
    for (int mt = 0; mt < 4; ++mt)
#pragma unroll
      for (int nt = 0; nt < 4; ++nt)
        acc[mt][nt] = __builtin_amdgcn_mfma_f32_16x16x32_bf16(
            af[mt], bfr[nt], acc[mt][nt], 0, 0, 0);
    __syncthreads();  // all waves done reading `cur`; next stage's loads drained
    cur ^= 1;
  }
#undef STAGE

  const float SCALE = 0.044194173824159216f;  // 512^-0.5
#pragma unroll
  for (int mt = 0; mt < 4; ++mt) {
#pragma unroll
    for (int nt = 0; nt < 4; ++nt) {
      int n = n0 + wn * 64 + nt * 16 + l16;
      float bn = 0.f;
      if constexpr (EPI == 0)
        bn = (n < 512) ? bias[n] : bias2_or_resid[n - 512];
#pragma unroll
      for (int reg = 0; reg < 4; ++reg) {
        int m = m0 + wm * 64 + mt * 16 + quad * 4 + reg;
        float v = acc[mt][nt][reg];
        size_t idx = (size_t)b * sOb + (size_t)m * ldo + n;
        if constexpr (EPI == 0) {
          ((u16*)Out)[idx] = f2bf(v + bn);
        } else if constexpr (EPI == 1) {
          ((u16*)Out)[idx] = f2bf(v + bias[m]);
        } else if constexpr (EPI == 2) {
          ((u16*)Out)[idx] = f2bf(v * SCALE);
        } else if constexpr (EPI == 3) {
          ((u16*)Out)[idx] = f2bf(v);
        } else {
          ((float*)Out)[idx] =
              v + bias[m] + bias2_or_resid[(size_t)b * sRb + (size_t)m * ldo + n];
        }
      }
    }
  }
}

// ---------------- Softmax over bf16 rows of Sc [nb*S][S], in place ------------
__global__ __launch_bounds__(256) void softmax_kernel(u16* __restrict__ Sc) {
  size_t row = blockIdx.x;
  u16* rp = Sc + row * (size_t)Ssp;
  uint2 u = ((const uint2*)rp)[threadIdx.x];  // 4 bf16
  const u16* ph = (const u16*)&u;
  float v0 = bf2f(ph[0]), v1 = bf2f(ph[1]), v2 = bf2f(ph[2]), v3 = bf2f(ph[3]);
  float mx = fmaxf(fmaxf(v0, v1), fmaxf(v2, v3));
#pragma unroll
  for (int off = 32; off > 0; off >>= 1) mx = fmaxf(mx, __shfl_xor(mx, off));
  __shared__ float sm[4];
  __shared__ float sd[4];
  int wid = threadIdx.x >> 6;
  if ((threadIdx.x & 63) == 0) sm[wid] = mx;
  __syncthreads();  // also: all row reads complete before any write below
  mx = fmaxf(fmaxf(sm[0], sm[1]), fmaxf(sm[2], sm[3]));
  float e0 = __expf(v0 - mx), e1 = __expf(v1 - mx);
  float e2 = __expf(v2 - mx), e3 = __expf(v3 - mx);
  float s = e0 + e1 + e2 + e3;
#pragma unroll
  for (int off = 32; off > 0; off >>= 1) s += __shfl_xor(s, off);
  if ((threadIdx.x & 63) == 0) sd[wid] = s;
  __syncthreads();
  s = sd[0] + sd[1] + sd[2] + sd[3];
  float inv = 1.f / s;
  union { u16 s4[4]; uint2 v2; } pk;
  pk.s4[0] = f2bf(e0 * inv); pk.s4[1] = f2bf(e1 * inv);
  pk.s4[2] = f2bf(e2 * inv); pk.s4[3] = f2bf(e3 * inv);
  ((uint2*)rp)[threadIdx.x] = pk.v2;
}

extern "C" void kernel_launch(void* const* d_in, const int* in_sizes, int n_in,
                              void* d_out, int out_size, void* d_ws, size_t ws_size,
                              hipStream_t stream) {
  (void)in_sizes; (void)n_in; (void)out_size;
  const float* x   = (const float*)d_in[0];
  const float* gns = (const float*)d_in[1];
  const float* gnb = (const float*)d_in[2];
  const float* Wq  = (const float*)d_in[3];
  const float* bq  = (const float*)d_in[4];
  const float* Wk  = (const float*)d_in[5];
  const float* bk  = (const float*)d_in[6];
  const float* Wv  = (const float*)d_in[7];
  const float* bv  = (const float*)d_in[8];
  const float* Wt  = (const float*)d_in[9];
  const float* bt  = (const float*)d_in[10];
  float* out = (float*)d_out;
  char* ws = (char*)d_ws;

  // Workspace:
  //   qkt @ 0MB   (64MB bf16 [b][s][1024], q|k fused) -> o_t aliases its start
  //               during chunked PV (o_t grows at half qkt's byte rate: safe)
  //   v   @ 64MB  (32MB bf16 [b][d][s])
  //   W_t @ 96MB  (4 x 0.5MB bf16 [d][c]: q,k,v,t -> Wq|Wk contiguous = fused N)
  //   stats @98MB (256KB float2)
  //   xt  @ 99MB  (32MB bf16 [b][s][c]) -> dead after projections
  //   Sc  @ 99MB  (NB*2MB bf16, overlays xt; softmax in place)
  const size_t QKSZ = (size_t)Bsz * Ssp * 1024 * 2;  // 64 MB
  u16* qkt = (u16*)ws;
  u16* vv  = (u16*)(ws + QKSZ);
  u16* Wts = (u16*)(ws + (96ull << 20));
  float2* stats = (float2*)(ws + (98ull << 20));
  u16* xt  = (u16*)(ws + (99ull << 20));
  u16* Sc  = xt;
  u16* ot  = qkt;

  int NB;  // batches per score chunk (Sc = NB*2MB @ 99MB); ws_size is constant
  if (ws_size >= (163ull << 20)) NB = 32;
  else if (ws_size >= (131ull << 20)) NB = 16;
  else NB = 8;

  const size_t WSZ = (size_t)Cch * Cch;
  u16* Wvt = Wts + 2 * WSZ;
  u16* Wtt = Wts + 3 * WSZ;

  const size_t sSC  = (size_t)Ssp * Cch;   // xt / o_t per-batch elems
  const size_t sQK  = (size_t)Ssp * 1024;  // qkt per-batch elems
  const size_t sCS  = (size_t)Cch * Ssp;   // v / x / out per-batch elems
  const size_t sScB = (size_t)Ssp * Ssp;   // score per-batch elems (bf16)
  dim3 blk(256);

  gnstats_kernel<<<dim3(Bsz * Grp), blk, 0, stream>>>(x, gns, gnb, stats);
  xpose_gn<<<dim3(Ssp / 64, Cch / 64, Bsz), blk, 0, stream>>>(x, stats, xt);
  wxpose<<<dim3(8, 8, 4), blk, 0, stream>>>(Wq, Wk, Wv, Wt, Wts);

  // fused q|k: m=s(1024), n=dq|dk(1024), k=c(512): A=xt, B=Wq_t|Wk_t
  mfma_nt<0><<<dim3(8, 8, Bsz), blk, 0, stream>>>(
      xt, sSC, Cch, Wts, 0, Cch, qkt, sQK, 1024, bq, bk, 0, Cch);
  // v: m=d(512), n=s(1024), k=c(512): A=Wv_t, B=xt -> v[d][s] + bias[m]
  mfma_nt<1><<<dim3(8, 4, Bsz), blk, 0, stream>>>(
      Wvt, 0, Cch, xt, sSC, Cch, vv, sCS, Ssp, bv, nullptr, 0, Cch);

  for (int b0 = 0; b0 < Bsz; b0 += NB) {
    int nb = (b0 + NB <= Bsz) ? NB : (Bsz - b0);
    // scores: m=s, n=s', k=d: A=q (qkt+0), B=k (qkt+512) -> Sc bf16 * C^-0.5
    mfma_nt<2><<<dim3(8, 8, nb), blk, 0, stream>>>(
        qkt + b0 * sQK, sQK, 1024, qkt + b0 * sQK + 512, sQK, 1024,
        Sc, sScB, Ssp, nullptr, nullptr, 0, Cch);
    softmax_kernel<<<dim3(nb * Ssp), blk, 0, stream>>>(Sc);
    // PV: m=s(1024), n=c(512), k=t(1024): A=P bf16, B=v -> o_t[s][c]
    mfma_nt<3><<<dim3(4, 8, nb), blk, 0, stream>>>(
        Sc, sScB, Ssp, vv + b0 * sCS, sCS, Ssp,
        ot + b0 * sSC, sSC, Cch, nullptr, nullptr, 0, Ssp);
  }

  // final: m=d(512), n=s(1024), k=c(512): A=Wt_t, B=o_t -> fp32 +bias[m]+x
  mfma_nt<4><<<dim3(8, 4, Bsz), blk, 0, stream>>>(
      Wtt, 0, Cch, ot, sSC, Cch, out, sCS, Ssp, bt, x, sCS, Cch);
}